// Round 5
// baseline (1572.973 us; speedup 1.0000x reference)
//
#include <hip/hip_runtime.h>
#include <math.h>

#define B_ 8
#define C_ 512
#define W_ 64
#define H_ 32
#define HID_ 256
#define G_ 1280
#define WH_ (W_*H_)           // 2048
#define CELL_STRIDE (B_*HID_) // 2048 floats per (w,h) cell in hbuf/cbuf
#define SENT 0xFFFFFFFFu      // memset(0xFF) pattern = negative quiet NaN; real h/c never NaN

typedef float v4f __attribute__((ext_vector_type(4)));

__device__ __forceinline__ float sigmoidf_(float x) {
    return 1.0f / (1.0f + __expf(-x));
}

__device__ __forceinline__ float tanhf_(float x) {
    float ax = fabsf(x);
    float e = __expf(-2.0f * ax);
    float t = (1.0f - e) / (1.0f + e);
    return copysignf(t, x);
}

// ---- device-coherent (sc0 sc1: bypass L1+L2, served at coherence point) ----
__device__ __forceinline__ void stg_byp1(float* p, float v) {
    asm volatile("global_store_dword %0, %1, off sc0 sc1" :: "v"(p), "v"(v) : "memory");
}
// canary: 2 dword bypass loads, one wait
__device__ __forceinline__ void ldg2_byp(const unsigned* p0, const unsigned* p1,
                                         unsigned& a, unsigned& b) {
    asm volatile("global_load_dword %0, %2, off sc0 sc1\n\t"
                 "global_load_dword %1, %3, off sc0 sc1\n\t"
                 "s_waitcnt vmcnt(0)"
                 : "=&v"(a), "=&v"(b)
                 : "v"(p0), "v"(p1)
                 : "memory");
}

__device__ __forceinline__ bool ok4(v4f v) {
    return (__float_as_uint(v.x) != SENT) & (__float_as_uint(v.y) != SENT) &
           (__float_as_uint(v.z) != SENT) & (__float_as_uint(v.w) != SENT);
}

// ---------------------------------------------------------------------------
// A0: transpose x (B,C,W,H) = [bc][wh] row-major  ->  xT [wh][bc]
// ---------------------------------------------------------------------------
__global__ __launch_bounds__(256) void k_transpose_x(const float* __restrict__ x,
                                                     float* __restrict__ xT) {
    __shared__ float tile[64][65];
    int bc0 = blockIdx.x * 64;
    int wh0 = blockIdx.y * 64;
    int xcol = threadIdx.x & 63;
    int yrow = threadIdx.x >> 6;
    for (int yy = yrow; yy < 64; yy += 4)
        tile[yy][xcol] = x[(size_t)(bc0 + yy) * WH_ + wh0 + xcol];
    __syncthreads();
    for (int yy = yrow; yy < 64; yy += 4)
        xT[(size_t)(wh0 + yy) * (B_*C_) + bc0 + xcol] = tile[xcol][yy];
}

// ---------------------------------------------------------------------------
// A: GEMM  xp[m][g] = sum_c A[m][c]*Wx[c][g] + bias[g],  m = wh*8+b (16384)
// ---------------------------------------------------------------------------
#define BM 64
#define BN 128
#define BK 32
#define AS_STRIDE 68
#define BS_STRIDE 132

__global__ __launch_bounds__(256) void k_xproj(const float* __restrict__ xT,
                                               const float* __restrict__ Wx,
                                               const float* __restrict__ bias,
                                               float* __restrict__ xp) {
    __shared__ float As[BK * AS_STRIDE];
    __shared__ float Bs[BK * BS_STRIDE];

    int bid = blockIdx.x;
    int xcd = bid & 7;
    int slot = bid >> 3;
    int mt = xcd * 32 + slot / 10;
    int nt = slot % 10;
    int m0 = mt * BM, n0 = nt * BN;
    int tid = threadIdx.x;

    int tm  = (tid >> 5) * 8;
    int tn4 = (tid & 31) * 4;

    float4 acc[8];
#pragma unroll
    for (int i = 0; i < 8; ++i) { acc[i].x = acc[i].y = acc[i].z = acc[i].w = 0.f; }

    int ar = tid >> 2, aq = tid & 3;
    int br = tid >> 3, bq = tid & 7;

    for (int kc = 0; kc < C_; kc += BK) {
        float4 av0 = *(const float4*)(xT + (size_t)(m0 + ar) * C_ + kc + aq * 4);
        float4 av1 = *(const float4*)(xT + (size_t)(m0 + ar) * C_ + kc + (aq + 4) * 4);
        float4 bv[4];
#pragma unroll
        for (int s = 0; s < 4; ++s)
            bv[s] = *(const float4*)(Wx + (size_t)(kc + br) * G_ + n0 + (bq + 8 * s) * 4);

        __syncthreads();
        As[(aq * 4 + 0) * AS_STRIDE + ar] = av0.x;
        As[(aq * 4 + 1) * AS_STRIDE + ar] = av0.y;
        As[(aq * 4 + 2) * AS_STRIDE + ar] = av0.z;
        As[(aq * 4 + 3) * AS_STRIDE + ar] = av0.w;
        As[((aq + 4) * 4 + 0) * AS_STRIDE + ar] = av1.x;
        As[((aq + 4) * 4 + 1) * AS_STRIDE + ar] = av1.y;
        As[((aq + 4) * 4 + 2) * AS_STRIDE + ar] = av1.z;
        As[((aq + 4) * 4 + 3) * AS_STRIDE + ar] = av1.w;
#pragma unroll
        for (int s = 0; s < 4; ++s)
            *(float4*)&Bs[br * BS_STRIDE + (bq + 8 * s) * 4] = bv[s];
        __syncthreads();

#pragma unroll
        for (int k = 0; k < BK; ++k) {
            float4 a0 = *(const float4*)&As[k * AS_STRIDE + tm];
            float4 a1 = *(const float4*)&As[k * AS_STRIDE + tm + 4];
            float4 b0 = *(const float4*)&Bs[k * BS_STRIDE + tn4];
            float am[8] = {a0.x, a0.y, a0.z, a0.w, a1.x, a1.y, a1.z, a1.w};
#pragma unroll
            for (int i = 0; i < 8; ++i) {
                acc[i].x += am[i] * b0.x;
                acc[i].y += am[i] * b0.y;
                acc[i].z += am[i] * b0.z;
                acc[i].w += am[i] * b0.w;
            }
        }
    }

    float4 bb = *(const float4*)(bias + n0 + tn4);
#pragma unroll
    for (int i = 0; i < 8; ++i) {
        float4 o;
        o.x = acc[i].x + bb.x; o.y = acc[i].y + bb.y;
        o.z = acc[i].z + bb.z; o.w = acc[i].w + bb.w;
        *(float4*)(xp + (size_t)(m0 + tm + i) * G_ + n0 + tn4) = o;
    }
}

// ---------------------------------------------------------------------------
// B: persistent wavefront scan. NEW grid: 512 blocks (2/CU), 512 threads.
// Structure is the r2-passing kernel VERBATIM (sentinel protocol, canary +
// batched stage, monolithic 8-wave GEMM, kq-pair fold, ownership reduce).
// Only the index arithmetic changed for NT=16:
//  * 32 row-pairs x 16 col-slices; bid swizzle (w0b=bid>>4) puts co-resident
//    pair (bid, bid+256) 16 rows apart -> 16-step phase skew, so one block's
//    GEMM fills the other's poll/visibility stalls (r2: 44% idle).
//  * per-thread: K-slice 16 (kq=tid>>4), cols c0=tid&15, wr[5][16] (80 regs,
//    half of r2) -> fits the <=128-reg tier for 16 waves/CU (launch_bounds
//    min 4 waves/SIMD).
// ---------------------------------------------------------------------------
#define NT 16
#define NSL 16                      // folded gp slices
#define GPS (NSL*80 + 8)            // 1288 floats per batch

__global__ __launch_bounds__(512, 4) void k_scan(const float* __restrict__ xp,
                                                 const float* __restrict__ Wh1,
                                                 const float* __restrict__ Wh2,
                                                 float* __restrict__ hbuf,
                                                 float* __restrict__ cbuf) {
    __shared__ float hs[2][B_ * HID_];        // 16 KB
    __shared__ float gp[B_ * GPS];            // 41.2 KB

    int w0b = blockIdx.x >> 4;      // 0..31
    int nt  = blockIdx.x & 15;      // 0..15
    int n0  = nt * NT;
    int tid = threadIdx.x;

    int kq  = tid >> 4;             // 0..31 (16-wide K slices over combined K=512)
    int c0  = tid & 15;
    int sel = kq >> 4;              // 0: Wh1/h_left (kq 0..15), 1: Wh2/h_up
    int kk0 = (kq & 15) * 16;
    const float* Wm = sel ? Wh2 : Wh1;
    const float* hbase = &hs[sel][0];
    int wv = tid >> 6;              // wave 0..7
    bool lo32 = (tid & 63) < 32;
    int sfold = wv * 2 + ((tid >> 4) & 1);   // folded slice id 0..15

    // ---- one-time: weights into registers (80 VGPRs) ----
    float wr[5][16];
#pragma unroll
    for (int g = 0; g < 5; ++g)
#pragma unroll
        for (int k = 0; k < 16; ++k)
            wr[g][k] = Wm[(size_t)(kk0 + k) * G_ + g * 256 + n0 + c0];

    int b2 = tid >> 4, nn2 = tid & 15;   // (b,c) ownership for tid<128
    bool cok = (tid < 128);
    int xob = b2 * G_ + n0 + nn2;        // xp offset base (per gate +g*256)
    int co  = b2 * HID_ + n0 + nn2;      // cell column offset
    int gr  = b2 * GPS + nn2;            // gp read base
    int gwb = sfold * 80 + c0;           // gp write base

    for (int rr = 0; rr < 2; ++rr) {
        int w = w0b + rr * 32;
        float creg = 0.f;            // c_left register carry (valid for tid<128)
        for (int h = 0; h < H_; ++h) {
            int wh = w * H_ + h;

            // ---- xp prefetch: owner threads load their 5 gate values ----
            float xpre[5];
            if (cok) {
                const float* xrow = xp + (size_t)wh * (B_ * G_) + xob;
#pragma unroll
                for (int g = 0; g < 5; ++g) xpre[g] = xrow[g * 256];
            }

            bool vl = (h > 0), vu = (w > 0);
            const float* pl = vl ? hbuf + (size_t)(wh - 1)  * CELL_STRIDE + tid * 4 : hbuf;
            const float* pu = vu ? hbuf + (size_t)(wh - H_) * CELL_STRIDE + tid * 4 : hbuf;
            const float* pc = (vu && cok) ? cbuf + (size_t)(wh - H_) * CELL_STRIDE + co : cbuf;

            // ---- phase 1: canary spin (lane 0 of each wave, 8B per retry) ----
            if ((tid & 63) == 0) {
                if (vl | vu) {
                    for (;;) {
                        unsigned a, bvv;
                        ldg2_byp((const unsigned*)pl, (const unsigned*)pu, a, bvv);
                        if ((((!vl)) | (a != SENT)) & (((!vu)) | (bvv != SENT))) break;
                        __builtin_amdgcn_s_sleep(2);
                    }
                }
            }

            // ---- phase 2: batched full stage + verify (usually 1 iteration) ----
            v4f l0 = {0.f, 0.f, 0.f, 0.f};
            v4f u0 = {0.f, 0.f, 0.f, 0.f};
            float cu = 0.f;
            bool needl = vl, needu = vu, needc = vu && cok;
            for (;;) {
                v4f tl, tu; float tc;
                asm volatile(
                    "global_load_dwordx4 %0, %3, off sc0 sc1\n\t"
                    "global_load_dwordx4 %1, %4, off sc0 sc1\n\t"
                    "global_load_dword %2, %5, off sc0 sc1\n\t"
                    "s_waitcnt vmcnt(0)"
                    : "=&v"(tl), "=&v"(tu), "=&v"(tc)
                    : "v"(pl), "v"(pu), "v"(pc)
                    : "memory");
                if (needl & ok4(tl)) { l0 = tl; needl = false; }
                if (needu & ok4(tu)) { u0 = tu; needu = false; }
                if (needc & (__float_as_uint(tc) != SENT)) { cu = tc; needc = false; }
                if (__ballot(needl | needu | needc) == 0) break;
                __builtin_amdgcn_s_sleep(1);
            }
            ((v4f*)hs[0])[tid] = l0;
            ((v4f*)hs[1])[tid] = u0;
            __syncthreads();                       // B1: hs ready

            // ---- GEMM: pure LDS + FMA (no VMEM) ----
            float acc[5][8];
#pragma unroll
            for (int g = 0; g < 5; ++g)
#pragma unroll
                for (int b = 0; b < 8; ++b) acc[g][b] = 0.f;

#pragma unroll
            for (int k4 = 0; k4 < 4; ++k4) {
#pragma unroll
                for (int b = 0; b < 8; ++b) {
                    float4 hv = *(const float4*)&hbase[b * HID_ + kk0 + k4 * 4]; // broadcast
#pragma unroll
                    for (int g = 0; g < 5; ++g) {
                        acc[g][b] += hv.x * wr[g][k4 * 4 + 0];
                        acc[g][b] += hv.y * wr[g][k4 * 4 + 1];
                        acc[g][b] += hv.z * wr[g][k4 * 4 + 2];
                        acc[g][b] += hv.w * wr[g][k4 * 4 + 3];
                    }
                }
            }

            // ---- in-wave kq-pair reduction (VALU pipe) + packed gp write ----
            // lanes i / i+32 hold partials of kq and kq+2 for the same c0;
            // swap+add gives the pair sum in both halves. lo half stores
            // values 0..19, hi half 20..39: 20 LDS stores per thread.
#pragma unroll
            for (int v = 0; v < 20; ++v) {
                const int ia = v, ib = v + 20;
                float xa = acc[ia >> 3][ia & 7], ya = xa;
                float xb = acc[ib >> 3][ib & 7], yb = xb;
                asm("v_permlane32_swap_b32 %0, %1" : "+v"(xa), "+v"(ya));
                asm("v_permlane32_swap_b32 %0, %1" : "+v"(xb), "+v"(yb));
                float sa = xa + ya;
                float sb = xb + yb;
                float val = lo32 ? sa : sb;
                const int offA = (ia & 7) * GPS + (ia >> 3) * 16;
                const int offB = (ib & 7) * GPS + (ib >> 3) * 16;
                gp[gwb + (lo32 ? offA : offB)] = val;
            }
            __syncthreads();                       // B2: gp ready, GEMM reads done

            // ---- ownership-aligned reduce + cell update (tid < 128) ----
            if (cok) {
                float gv[5];
#pragma unroll
                for (int g = 0; g < 5; ++g) {
                    float s = xpre[g];
#pragma unroll
                    for (int q = 0; q < NSL; ++q)
                        s += gp[gr + q * 80 + g * 16];
                    gv[g] = s;
                }
                float iv = sigmoidf_(gv[0]);
                float f1 = sigmoidf_(gv[1]);
                float f2 = sigmoidf_(gv[2]);
                float ov = sigmoidf_(gv[3]);
                float cd = tanhf_(gv[4]);
                float cv = iv * cd + f1 * creg + f2 * cu;
                float hh = ov * tanhf_(cv);
                creg = cv;
                stg_byp1(cbuf + (size_t)wh * CELL_STRIDE + co, cv);
                stg_byp1(hbuf + (size_t)wh * CELL_STRIDE + co, hh);
            }
            // no trailing barrier: next step's hs writes are post-B2 for every
            // wave (GEMM reads done); next gp writes are post-B1 (reduce done).
        }
    }
}

// ---------------------------------------------------------------------------
// C1: BN partial stats
// ---------------------------------------------------------------------------
__global__ __launch_bounds__(256) void k_stats(const float* __restrict__ hbuf,
                                               float* __restrict__ ssum,
                                               float* __restrict__ ssq) {
    int t = threadIdx.x;
    size_t r0 = (size_t)blockIdx.x * 64;
    float s = 0.f, q = 0.f;
    for (int r = 0; r < 64; ++r) {
        float v = hbuf[(r0 + r) * HID_ + t];
        s += v; q += v * v;
    }
    atomicAdd(&ssum[t], s);
    atomicAdd(&ssq[t], q);
}

__global__ void k_finstats(const float* __restrict__ ssum, const float* __restrict__ ssq,
                           float* __restrict__ mean, float* __restrict__ rinv) {
    int t = threadIdx.x;
    const float inv_n = 1.0f / 16384.0f;
    float m = ssum[t] * inv_n;
    float v = ssq[t] * inv_n - m * m;
    mean[t] = m;
    rinv[t] = rsqrtf(v + 1e-5f);
}

// ---------------------------------------------------------------------------
// C2: transpose (wh,b,n) -> (b,n,wh); fused BN+tanh for out
// ---------------------------------------------------------------------------
__global__ __launch_bounds__(256) void k_out(const float* __restrict__ hbuf,
                                             const float* __restrict__ cbuf,
                                             const float* __restrict__ mean,
                                             const float* __restrict__ rinv,
                                             const float* __restrict__ gamma,
                                             const float* __restrict__ beta,
                                             float* __restrict__ outp) {
    __shared__ float tile[64][65];
    int bi = blockIdx.x;
    int b = bi >> 7;
    int rem = bi & 127;
    int wh0 = (rem >> 2) * 64;
    int n0 = (rem & 3) * 64;
    int xcol = threadIdx.x & 63;
    int yrow = threadIdx.x >> 6;

    float* out0   = outp;
    float* state0 = outp + (size_t)B_ * HID_ * WH_;
    float* cell0  = state0 + (size_t)B_ * HID_ * WH_;

    for (int yy = yrow; yy < 64; yy += 4)
        tile[yy][xcol] = hbuf[((size_t)(wh0 + yy) * B_ + b) * HID_ + n0 + xcol];
    __syncthreads();
    for (int yy = yrow; yy < 64; yy += 4) {
        int n = n0 + yy;
        float sv = tile[xcol][yy];
        size_t oidx = ((size_t)b * HID_ + n) * WH_ + wh0 + xcol;
        state0[oidx] = sv;
        float xn = (sv - mean[n]) * rinv[n];
        out0[oidx] = tanhf_(xn * gamma[n] + beta[n]);
    }
    __syncthreads();

    for (int yy = yrow; yy < 64; yy += 4)
        tile[yy][xcol] = cbuf[((size_t)(wh0 + yy) * B_ + b) * HID_ + n0 + xcol];
    __syncthreads();

    for (int yy = yrow; yy < 64; yy += 4) {
        int n = n0 + yy;
        size_t oidx = ((size_t)b * HID_ + n) * WH_ + wh0 + xcol;
        cell0[oidx] = tile[xcol][yy];
    }
}

// ---------------------------------------------------------------------------
extern "C" void kernel_launch(void* const* d_in, const int* in_sizes, int n_in,
                              void* d_out, int out_size, void* d_ws, size_t ws_size,
                              hipStream_t stream) {
    const float* x     = (const float*)d_in[0];
    const float* Wx    = (const float*)d_in[1];
    const float* Wh1   = (const float*)d_in[2];
    const float* Wh2   = (const float*)d_in[3];
    const float* bias  = (const float*)d_in[4];
    const float* gamma = (const float*)d_in[5];
    const float* beta  = (const float*)d_in[6];
    float* out = (float*)d_out;
    float* ws  = (float*)d_ws;

    float* xp   = ws;                       // 20,971,520 floats
    float* xT   = ws + 20971520;            // 8,388,608 floats (dead after xproj)
    float* hbuf = xT;                       // alias (4,194,304 floats)
    float* cbuf = xT + 4194304;             // alias (4,194,304 floats)
    float* ssum = ws + 29360128;
    float* ssq  = ssum + 256;
    float* mean = ssum + 512;
    float* rinv = ssum + 768;

    k_transpose_x<<<dim3(64, 32), 256, 0, stream>>>(x, xT);
    k_xproj<<<2560, 256, 0, stream>>>(xT, Wx, bias, xp);

    hipMemsetAsync(ssum, 0, 1024 * sizeof(float), stream);
    // sentinel-fill hbuf+cbuf (contiguous 8M floats); runs after xproj (alias)
    hipMemsetAsync(hbuf, 0xFF, (size_t)8388608 * sizeof(float), stream);

    k_scan<<<512, 512, 0, stream>>>(xp, Wh1, Wh2, hbuf, cbuf);

    k_stats<<<256, 256, 0, stream>>>(hbuf, ssum, ssq);
    k_finstats<<<1, 256, 0, stream>>>(ssum, ssq, mean, rinv);
    k_out<<<8 * 32 * 4, 256, 0, stream>>>(hbuf, cbuf, mean, rinv, gamma, beta, out);
}

// Round 9
// 828.454 us; speedup vs baseline: 1.8987x; 1.8987x over previous
//
#include <hip/hip_runtime.h>
#include <math.h>

#define B_ 8
#define C_ 512
#define W_ 64
#define H_ 32
#define HID_ 256
#define G_ 1280
#define WH_ (W_*H_)           // 2048
#define CELL_STRIDE (B_*HID_) // 2048 floats per (w,h) cell in hbuf/cbuf
#define SENT 0xFFFFFFFFu      // memset(0xFF) pattern = negative quiet NaN; real h/c never NaN

typedef float v4f __attribute__((ext_vector_type(4)));
typedef __attribute__((ext_vector_type(8))) short bf16x8;   // guide §3 frag_ab
typedef __attribute__((ext_vector_type(4))) float f32x4;    // guide §3 frag_cd

__device__ __forceinline__ float sigmoidf_(float x) {
    return 1.0f / (1.0f + __expf(-x));
}

__device__ __forceinline__ float tanhf_(float x) {
    float ax = fabsf(x);
    float e = __expf(-2.0f * ax);
    float t = (1.0f - e) / (1.0f + e);
    return copysignf(t, x);
}

__device__ __forceinline__ unsigned short f2bf(float f) {   // RNE fp32->bf16
    unsigned u = __float_as_uint(f);
    u = u + 0x7FFFu + ((u >> 16) & 1u);
    return (unsigned short)(u >> 16);
}
__device__ __forceinline__ float bf2f(unsigned short h) {
    return __uint_as_float(((unsigned)h) << 16);
}

// ---- device-coherent (sc0 sc1: bypass L1+L2, served at coherence point) ----
__device__ __forceinline__ void stg_byp1(float* p, float v) {
    asm volatile("global_store_dword %0, %1, off sc0 sc1" :: "v"(p), "v"(v) : "memory");
}
// canary: 2 dword bypass loads, one wait
__device__ __forceinline__ void ldg2_byp(const unsigned* p0, const unsigned* p1,
                                         unsigned& a, unsigned& b) {
    asm volatile("global_load_dword %0, %2, off sc0 sc1\n\t"
                 "global_load_dword %1, %3, off sc0 sc1\n\t"
                 "s_waitcnt vmcnt(0)"
                 : "=&v"(a), "=&v"(b)
                 : "v"(p0), "v"(p1)
                 : "memory");
}

__device__ __forceinline__ bool ok4(v4f v) {
    return (__float_as_uint(v.x) != SENT) & (__float_as_uint(v.y) != SENT) &
           (__float_as_uint(v.z) != SENT) & (__float_as_uint(v.w) != SENT);
}

// ---------------------------------------------------------------------------
// A0: transpose x (B,C,W,H) -> split-bf16 xTh/xTl [wh*8+b][c]
// hi = bf16(v), lo = bf16(v - hi): v = hi + lo + O(2^-17 |v|)
// ---------------------------------------------------------------------------
__global__ __launch_bounds__(256) void k_transpose_x(const float* __restrict__ x,
                                                     unsigned short* __restrict__ xTh,
                                                     unsigned short* __restrict__ xTl) {
    __shared__ float tile[64][65];
    int bc0 = blockIdx.x * 64;
    int wh0 = blockIdx.y * 64;
    int xcol = threadIdx.x & 63;
    int yrow = threadIdx.x >> 6;
    for (int yy = yrow; yy < 64; yy += 4)
        tile[yy][xcol] = x[(size_t)(bc0 + yy) * WH_ + wh0 + xcol];
    __syncthreads();
    for (int yy = yrow; yy < 64; yy += 4) {
        float v = tile[xcol][yy];
        unsigned short hi = f2bf(v);
        unsigned short lo = f2bf(v - bf2f(hi));
        size_t idx = (size_t)(wh0 + yy) * (B_*C_) + bc0 + xcol;
        xTh[idx] = hi;
        xTl[idx] = lo;
    }
}

// ---------------------------------------------------------------------------
// A1: transpose Wx [k=512][n=1280] -> split-bf16 WxTh/WxTl [n][k]
// ---------------------------------------------------------------------------
__global__ __launch_bounds__(256) void k_wxT(const float* __restrict__ Wx,
                                             unsigned short* __restrict__ WxTh,
                                             unsigned short* __restrict__ WxTl) {
    __shared__ float tile[64][65];
    int n0 = blockIdx.x * 64;
    int k0 = blockIdx.y * 64;
    int xcol = threadIdx.x & 63;
    int yrow = threadIdx.x >> 6;
    for (int yy = yrow; yy < 64; yy += 4)
        tile[yy][xcol] = Wx[(size_t)(k0 + yy) * G_ + n0 + xcol];
    __syncthreads();
    for (int yy = yrow; yy < 64; yy += 4) {
        float v = tile[xcol][yy];
        unsigned short hi = f2bf(v);
        unsigned short lo = f2bf(v - bf2f(hi));
        size_t idx = (size_t)(n0 + yy) * C_ + k0 + xcol;
        WxTh[idx] = hi;
        WxTl[idx] = lo;
    }
}

// ---------------------------------------------------------------------------
// A2: split-bf16 MFMA GEMM  xp = (Ah+Al)(Bh+Bl)^T + bias, dropping Al*Bl
// (3 MFMAs/frag-pair: ~fp32-grade input precision, error ~2^-16 per product).
// M=16384, N=1280, K=512. Tile 128x128, BK=32, 256 thr, wave tile 64x64.
// Staging/fragment structure = r8 (validated: r8 computed finite approx
// result; only precision was short). C/D: col=lane&15, row=(lane>>4)*4+reg.
// ---------------------------------------------------------------------------
#define XAS 40   // LDS row stride in bf16 elems (80B -> conflict-lite)

__global__ __launch_bounds__(256) void k_xproj_mfma(const unsigned short* __restrict__ xTh,
                                                    const unsigned short* __restrict__ xTl,
                                                    const unsigned short* __restrict__ WxTh,
                                                    const unsigned short* __restrict__ WxTl,
                                                    const float* __restrict__ bias,
                                                    float* __restrict__ xp) {
    __shared__ unsigned short Ash[128 * XAS];   // 10.2 KB each
    __shared__ unsigned short Asl[128 * XAS];
    __shared__ unsigned short Bsh[128 * XAS];
    __shared__ unsigned short Bsl[128 * XAS];

    int bid = blockIdx.x;
    int nt2 = bid % 10;
    int mt  = bid / 10;
    int m0 = mt * 128, n0 = nt2 * 128;
    int tid = threadIdx.x;
    int lane = tid & 63;
    int wave = tid >> 6;
    int wm = (wave >> 1) * 64;     // wave row offset in tile
    int wn = (wave & 1) * 64;      // wave col offset
    int r16 = lane & 15;
    int kg  = lane >> 4;           // 0..3

    int srow = tid >> 1;           // staging row 0..127
    int sh   = (tid & 1) * 16;     // staging k-half (16 bf16 via 2x uint4)

    f32x4 acc[4][4];
#pragma unroll
    for (int i = 0; i < 4; ++i)
#pragma unroll
        for (int j = 0; j < 4; ++j)
            acc[i][j] = (f32x4)0.f;

    const unsigned short* agh = xTh  + (size_t)(m0 + srow) * C_ + sh;
    const unsigned short* agl = xTl  + (size_t)(m0 + srow) * C_ + sh;
    const unsigned short* bgh = WxTh + (size_t)(n0 + srow) * C_ + sh;
    const unsigned short* bgl = WxTl + (size_t)(n0 + srow) * C_ + sh;

    for (int kc = 0; kc < C_; kc += 32) {
        uint4 ah0 = *(const uint4*)(agh + kc);
        uint4 ah1 = *(const uint4*)(agh + kc + 8);
        uint4 al0 = *(const uint4*)(agl + kc);
        uint4 al1 = *(const uint4*)(agl + kc + 8);
        uint4 bh0 = *(const uint4*)(bgh + kc);
        uint4 bh1 = *(const uint4*)(bgh + kc + 8);
        uint4 bl0 = *(const uint4*)(bgl + kc);
        uint4 bl1 = *(const uint4*)(bgl + kc + 8);
        __syncthreads();                           // prior frag reads done
        *(uint4*)&Ash[srow * XAS + sh]     = ah0;
        *(uint4*)&Ash[srow * XAS + sh + 8] = ah1;
        *(uint4*)&Asl[srow * XAS + sh]     = al0;
        *(uint4*)&Asl[srow * XAS + sh + 8] = al1;
        *(uint4*)&Bsh[srow * XAS + sh]     = bh0;
        *(uint4*)&Bsh[srow * XAS + sh + 8] = bh1;
        *(uint4*)&Bsl[srow * XAS + sh]     = bl0;
        *(uint4*)&Bsl[srow * XAS + sh + 8] = bl1;
        __syncthreads();                           // tiles ready

        bf16x8 afh[4], afl[4], bfh[4], bfl[4];
#pragma unroll
        for (int i = 0; i < 4; ++i) {
            afh[i] = *(const bf16x8*)&Ash[(wm + i * 16 + r16) * XAS + kg * 8];
            afl[i] = *(const bf16x8*)&Asl[(wm + i * 16 + r16) * XAS + kg * 8];
        }
#pragma unroll
        for (int j = 0; j < 4; ++j) {
            bfh[j] = *(const bf16x8*)&Bsh[(wn + j * 16 + r16) * XAS + kg * 8];
            bfl[j] = *(const bf16x8*)&Bsl[(wn + j * 16 + r16) * XAS + kg * 8];
        }
#pragma unroll
        for (int i = 0; i < 4; ++i)
#pragma unroll
            for (int j = 0; j < 4; ++j) {
                acc[i][j] = __builtin_amdgcn_mfma_f32_16x16x32_bf16(afh[i], bfh[j], acc[i][j], 0, 0, 0);
                acc[i][j] = __builtin_amdgcn_mfma_f32_16x16x32_bf16(afh[i], bfl[j], acc[i][j], 0, 0, 0);
                acc[i][j] = __builtin_amdgcn_mfma_f32_16x16x32_bf16(afl[i], bfh[j], acc[i][j], 0, 0, 0);
            }
    }

    // epilogue: D row = kg*4 + q, col = r16 (verified C/D mapping)
#pragma unroll
    for (int j = 0; j < 4; ++j) {
        int cb = n0 + wn + j * 16 + r16;
        float bb = bias[cb];
#pragma unroll
        for (int i = 0; i < 4; ++i) {
            int mb = m0 + wm + i * 16 + kg * 4;
#pragma unroll
            for (int q = 0; q < 4; ++q)
                xp[(size_t)(mb + q) * G_ + cb] = acc[i][j][q] + bb;
        }
    }
}

// ---------------------------------------------------------------------------
// B: persistent wavefront scan. 256 blocks (1/CU), 512 threads.
// r2 PASSING kernel VERBATIM (641us). UNTOUCHED.
// ---------------------------------------------------------------------------
#define NT 32
#define NWV 8                       // gp slices after in-wave pair reduction
#define GPS (NWV*160 + 8)           // 1288 floats per batch

__global__ __launch_bounds__(512, 2) void k_scan(const float* __restrict__ xp,
                                                 const float* __restrict__ Wh1,
                                                 const float* __restrict__ Wh2,
                                                 float* __restrict__ hbuf,
                                                 float* __restrict__ cbuf) {
    __shared__ float hs[2][B_ * HID_];        // 16 KB
    __shared__ float gp[B_ * GPS];            // 41.2 KB

    int w0b = blockIdx.x >> 3;
    int nt  = blockIdx.x & 7;
    int n0  = nt * NT;
    int tid = threadIdx.x;

    int kq  = tid >> 5;             // 0..15
    int c0  = tid & 31;
    int sel = kq >> 3;              // 0: Wh1/h_left, 1: Wh2/h_up (wave-uniform)
    int kk0 = (kq & 7) * 32;
    const float* Wm = sel ? Wh2 : Wh1;
    const float* hbase = &hs[sel][0];
    int wv = tid >> 6;              // wave id 0..7 (= kq-pair slice)
    bool lo32 = (tid & 63) < 32;

    // ---- one-time: weights into registers (160 VGPRs/AGPRs) ----
    float wr[5][32];
#pragma unroll
    for (int g = 0; g < 5; ++g)
#pragma unroll
        for (int k = 0; k < 32; ++k)
            wr[g][k] = Wm[(size_t)(kk0 + k) * G_ + g * 256 + n0 + c0];

    int b2 = tid >> 5, nn2 = tid & 31;   // (b,c) ownership for tid<256
    bool cok = (tid < 256);
    int xob = b2 * G_ + n0 + nn2;        // xp offset base (per gate +g*256)
    int co  = b2 * HID_ + n0 + nn2;      // cell column offset
    int gr  = b2 * GPS + nn2;            // gp read base
    int gwb = wv * 160 + c0;             // gp write base (slice = wave)

    for (int rr = 0; rr < 2; ++rr) {
        int w = w0b + rr * 32;
        float creg = 0.f;            // c_left register carry (valid for tid<256)
        for (int h = 0; h < H_; ++h) {
            int wh = w * H_ + h;

            // ---- xp prefetch: owner threads load their 5 gate values ----
            float xpre[5];
            if (cok) {
                const float* xrow = xp + (size_t)wh * (B_ * G_) + xob;
#pragma unroll
                for (int g = 0; g < 5; ++g) xpre[g] = xrow[g * 256];
            }

            bool vl = (h > 0), vu = (w > 0);
            const float* pl = vl ? hbuf + (size_t)(wh - 1)  * CELL_STRIDE + tid * 4 : hbuf;
            const float* pu = vu ? hbuf + (size_t)(wh - H_) * CELL_STRIDE + tid * 4 : hbuf;
            const float* pc = (vu && cok) ? cbuf + (size_t)(wh - H_) * CELL_STRIDE + co : cbuf;

            // ---- phase 1: canary spin (lane 0 of each wave, 8B per retry) ----
            if ((tid & 63) == 0) {
                if (vl | vu) {
                    for (;;) {
                        unsigned a, bvv;
                        ldg2_byp((const unsigned*)pl, (const unsigned*)pu, a, bvv);
                        if ((((!vl)) | (a != SENT)) & (((!vu)) | (bvv != SENT))) break;
                        __builtin_amdgcn_s_sleep(2);
                    }
                }
            }

            // ---- phase 2: batched full stage + verify (usually 1 iteration) ----
            v4f l0 = {0.f, 0.f, 0.f, 0.f};
            v4f u0 = {0.f, 0.f, 0.f, 0.f};
            float cu = 0.f;
            bool needl = vl, needu = vu, needc = vu && cok;
            for (;;) {
                v4f tl, tu; float tc;
                asm volatile(
                    "global_load_dwordx4 %0, %3, off sc0 sc1\n\t"
                    "global_load_dwordx4 %1, %4, off sc0 sc1\n\t"
                    "global_load_dword %2, %5, off sc0 sc1\n\t"
                    "s_waitcnt vmcnt(0)"
                    : "=&v"(tl), "=&v"(tu), "=&v"(tc)
                    : "v"(pl), "v"(pu), "v"(pc)
                    : "memory");
                if (needl & ok4(tl)) { l0 = tl; needl = false; }
                if (needu & ok4(tu)) { u0 = tu; needu = false; }
                if (needc & (__float_as_uint(tc) != SENT)) { cu = tc; needc = false; }
                if (__ballot(needl | needu | needc) == 0) break;
                __builtin_amdgcn_s_sleep(1);
            }
            ((v4f*)hs[0])[tid] = l0;
            ((v4f*)hs[1])[tid] = u0;
            __syncthreads();                       // B1: hs ready

            // ---- GEMM: pure LDS + FMA (no VMEM) ----
            float acc[5][8];
#pragma unroll
            for (int g = 0; g < 5; ++g)
#pragma unroll
                for (int b = 0; b < 8; ++b) acc[g][b] = 0.f;

#pragma unroll
            for (int k4 = 0; k4 < 8; ++k4) {
#pragma unroll
                for (int b = 0; b < 8; ++b) {
                    float4 hv = *(const float4*)&hbase[b * HID_ + kk0 + k4 * 4]; // broadcast
#pragma unroll
                    for (int g = 0; g < 5; ++g) {
                        acc[g][b] += hv.x * wr[g][k4 * 4 + 0];
                        acc[g][b] += hv.y * wr[g][k4 * 4 + 1];
                        acc[g][b] += hv.z * wr[g][k4 * 4 + 2];
                        acc[g][b] += hv.w * wr[g][k4 * 4 + 3];
                    }
                }
            }

            // ---- in-wave kq-pair reduction (VALU pipe) + packed gp write ----
#pragma unroll
            for (int v = 0; v < 20; ++v) {
                const int ia = v, ib = v + 20;
                float xa = acc[ia >> 3][ia & 7], ya = xa;
                float xb = acc[ib >> 3][ib & 7], yb = xb;
                asm("v_permlane32_swap_b32 %0, %1" : "+v"(xa), "+v"(ya));
                asm("v_permlane32_swap_b32 %0, %1" : "+v"(xb), "+v"(yb));
                float sa = xa + ya;
                float sb = xb + yb;
                float val = lo32 ? sa : sb;
                const int offA = (ia & 7) * GPS + (ia >> 3) * 32;
                const int offB = (ib & 7) * GPS + (ib >> 3) * 32;
                gp[gwb + (lo32 ? offA : offB)] = val;
            }
            __syncthreads();                       // B2: gp ready, GEMM reads done

            // ---- ownership-aligned reduce + cell update (tid < 256) ----
            if (cok) {
                float gv[5];
#pragma unroll
                for (int g = 0; g < 5; ++g) {
                    float s = xpre[g];
#pragma unroll
                    for (int q = 0; q < NWV; ++q)
                        s += gp[gr + q * 160 + g * 32];
                    gv[g] = s;
                }
                float iv = sigmoidf_(gv[0]);
                float f1 = sigmoidf_(gv[1]);
                float f2 = sigmoidf_(gv[2]);
                float ov = sigmoidf_(gv[3]);
                float cd = tanhf_(gv[4]);
                float cv = iv * cd + f1 * creg + f2 * cu;
                float hh = ov * tanhf_(cv);
                creg = cv;
                stg_byp1(cbuf + (size_t)wh * CELL_STRIDE + co, cv);
                stg_byp1(hbuf + (size_t)wh * CELL_STRIDE + co, hh);
            }
            // no trailing barrier: next step's hs writes are post-B2 for every
            // wave (GEMM reads done); next gp writes are post-B1 (reduce done).
        }
    }
}

// ---------------------------------------------------------------------------
// C1: BN partial stats
// ---------------------------------------------------------------------------
__global__ __launch_bounds__(256) void k_stats(const float* __restrict__ hbuf,
                                               float* __restrict__ ssum,
                                               float* __restrict__ ssq) {
    int t = threadIdx.x;
    size_t r0 = (size_t)blockIdx.x * 64;
    float s = 0.f, q = 0.f;
    for (int r = 0; r < 64; ++r) {
        float v = hbuf[(r0 + r) * HID_ + t];
        s += v; q += v * v;
    }
    atomicAdd(&ssum[t], s);
    atomicAdd(&ssq[t], q);
}

__global__ void k_finstats(const float* __restrict__ ssum, const float* __restrict__ ssq,
                           float* __restrict__ mean, float* __restrict__ rinv) {
    int t = threadIdx.x;
    const float inv_n = 1.0f / 16384.0f;
    float m = ssum[t] * inv_n;
    float v = ssq[t] * inv_n - m * m;
    mean[t] = m;
    rinv[t] = rsqrtf(v + 1e-5f);
}

// ---------------------------------------------------------------------------
// C2: transpose (wh,b,n) -> (b,n,wh); fused BN+tanh for out
// ---------------------------------------------------------------------------
__global__ __launch_bounds__(256) void k_out(const float* __restrict__ hbuf,
                                             const float* __restrict__ cbuf,
                                             const float* __restrict__ mean,
                                             const float* __restrict__ rinv,
                                             const float* __restrict__ gamma,
                                             const float* __restrict__ beta,
                                             float* __restrict__ outp) {
    __shared__ float tile[64][65];
    int bi = blockIdx.x;
    int b = bi >> 7;
    int rem = bi & 127;
    int wh0 = (rem >> 2) * 64;
    int n0 = (rem & 3) * 64;
    int xcol = threadIdx.x & 63;
    int yrow = threadIdx.x >> 6;

    float* out0   = outp;
    float* state0 = outp + (size_t)B_ * HID_ * WH_;
    float* cell0  = state0 + (size_t)B_ * HID_ * WH_;

    for (int yy = yrow; yy < 64; yy += 4)
        tile[yy][xcol] = hbuf[((size_t)(wh0 + yy) * B_ + b) * HID_ + n0 + xcol];
    __syncthreads();
    for (int yy = yrow; yy < 64; yy += 4) {
        int n = n0 + yy;
        float sv = tile[xcol][yy];
        size_t oidx = ((size_t)b * HID_ + n) * WH_ + wh0 + xcol;
        state0[oidx] = sv;
        float xn = (sv - mean[n]) * rinv[n];
        out0[oidx] = tanhf_(xn * gamma[n] + beta[n]);
    }
    __syncthreads();

    for (int yy = yrow; yy < 64; yy += 4)
        tile[yy][xcol] = cbuf[((size_t)(wh0 + yy) * B_ + b) * HID_ + n0 + xcol];
    __syncthreads();

    for (int yy = yrow; yy < 64; yy += 4) {
        int n = n0 + yy;
        size_t oidx = ((size_t)b * HID_ + n) * WH_ + wh0 + xcol;
        cell0[oidx] = tile[xcol][yy];
    }
}

// ---------------------------------------------------------------------------
extern "C" void kernel_launch(void* const* d_in, const int* in_sizes, int n_in,
                              void* d_out, int out_size, void* d_ws, size_t ws_size,
                              hipStream_t stream) {
    const float* x     = (const float*)d_in[0];
    const float* Wx    = (const float*)d_in[1];
    const float* Wh1   = (const float*)d_in[2];
    const float* Wh2   = (const float*)d_in[3];
    const float* bias  = (const float*)d_in[4];
    const float* gamma = (const float*)d_in[5];
    const float* beta  = (const float*)d_in[6];
    float* out = (float*)d_out;
    float* ws  = (float*)d_ws;

    float* xp   = ws;                       // 20,971,520 floats (16384x1280)
    float* hbuf = ws + 20971520;            // 4,194,304 floats
    float* cbuf = ws + 25165824;            // 4,194,304 floats
    float* ssum = ws + 29360128;
    float* ssq  = ssum + 256;
    float* mean = ssum + 512;
    float* rinv = ssum + 768;

    // split-bf16 staging lives in d_out used as scratch (151MB; k_out fully
    // overwrites all 3 outputs at the end, so this is safe).
    unsigned short* sb   = (unsigned short*)out;
    unsigned short* xTh  = sb;                        // 8,388,608 ushorts
    unsigned short* xTl  = sb + 8388608;              // 8,388,608
    unsigned short* WxTh = sb + 16777216;             //   655,360
    unsigned short* WxTl = sb + 17432576;             //   655,360  (= 36.2MB total)

    k_transpose_x<<<dim3(64, 32), 256, 0, stream>>>(x, xTh, xTl);
    k_wxT<<<dim3(20, 8), 256, 0, stream>>>(Wx, WxTh, WxTl);
    k_xproj_mfma<<<1280, 256, 0, stream>>>(xTh, xTl, WxTh, WxTl, bias, xp);

    hipMemsetAsync(ssum, 0, 1024 * sizeof(float), stream);
    hipMemsetAsync(hbuf, 0xFF, (size_t)8388608 * sizeof(float), stream);

    k_scan<<<256, 512, 0, stream>>>(xp, Wh1, Wh2, hbuf, cbuf);

    k_stats<<<256, 256, 0, stream>>>(hbuf, ssum, ssq);
    k_finstats<<<1, 256, 0, stream>>>(ssum, ssq, mean, rinv);
    k_out<<<8 * 32 * 4, 256, 0, stream>>>(hbuf, cbuf, mean, rinv, gamma, beta, out);
}